// Round 1
// baseline (10347.318 us; speedup 1.0000x reference)
//
#include <hip/hip_runtime.h>
#include <hip/hip_fp16.h>

#define Bn 128
#define Tn 2048
#define Hn 128
#define Gn 512            // 4*H gate rows
#define CHUNK 512
#define NCHUNK (Tn / CHUNK)

static_assert(CHUNK == 512 && Gn == 512, "index shifts assume 512");

__device__ __forceinline__ float sigmoid_f(float x) { return 1.f / (1.f + __expf(-x)); }
__device__ __forceinline__ float tanh_f(float x) {
  float e = __expf(-2.f * fabsf(x));
  float r = (1.f - e) / (1.f + e);
  return copysignf(r, x);
}

// ---------------- layer-0 input gates: xg = x @ Wih0^T + bih + bhh (K=4) ---
__global__ __launch_bounds__(256) void k_xg0(
    const float* __restrict__ x, const float* __restrict__ W,
    const float* __restrict__ b1, const float* __restrict__ b2,
    __half* __restrict__ xg, int chunk)
{
  int flat = blockIdx.x * 256 + threadIdx.x;       // (b*CHUNK + tc)*Gn + g
  int g  = flat & (Gn - 1);
  int tc = (flat >> 9) & (CHUNK - 1);
  int b  = flat >> 18;
  int t  = chunk * CHUNK + tc;
  float4 xv = *(const float4*)(x + ((size_t)b * Tn + t) * 4);
  float4 wv = *(const float4*)(W + g * 4);
  float s = b1[g] + b2[g] + xv.x * wv.x + xv.y * wv.y + xv.z * wv.z + xv.w * wv.w;
  xg[flat] = __float2half(s);
}

// ---------------- layers 1,2 input gates: xg = h_prev @ Wih^T + biases -----
// 64(t) x 64(g) tile, K=128 in one LDS pass. Rotation swizzle keeps float4
// LDS reads 16B-aligned and <=2-way bank conflicted.
#define SWZ(r, k) (((k) + ((((r) >> 2) << 2))) & (Hn - 1))

__global__ __launch_bounds__(256) void k_xgh(
    const __half* __restrict__ hseq, const float* __restrict__ W,
    const float* __restrict__ b1, const float* __restrict__ b2,
    __half* __restrict__ xg, int chunk)
{
  __shared__ float As[64][Hn];   // h tile   [t][k] (swizzled)
  __shared__ float Bs[64][Hn];   // Wih tile [g][k] (swizzled)
  const int tid = threadIdx.x;
  const int g0 = blockIdx.x * 64;
  const int t0 = blockIdx.y * 64;          // offset within chunk
  const int b  = blockIdx.z;

  const __half* Ab = hseq + ((size_t)b * Tn + chunk * CHUNK + t0) * Hn;
  const float*  Bb = W + (size_t)g0 * Hn;

#pragma unroll
  for (int p = 0; p < 8; ++p) {            // stage A: 64x128 halves -> fp32
    int f = p * 1024 + tid * 4;
    ushort4 v = ((const ushort4*)Ab)[f >> 2];
    int r = f >> 7, k = f & (Hn - 1);
    float* dst = &As[r][SWZ(r, k)];
    dst[0] = __half2float(*(const __half*)&v.x);
    dst[1] = __half2float(*(const __half*)&v.y);
    dst[2] = __half2float(*(const __half*)&v.z);
    dst[3] = __half2float(*(const __half*)&v.w);
  }
#pragma unroll
  for (int p = 0; p < 8; ++p) {            // stage B: 64x128 floats
    int f = p * 1024 + tid * 4;
    float4 v = ((const float4*)Bb)[f >> 2];
    int r = f >> 7, k = f & (Hn - 1);
    *(float4*)&Bs[r][SWZ(r, k)] = v;
  }
  __syncthreads();

  const int tg = tid & 15, tt = tid >> 4;
  float acc[4][4] = {};
#pragma unroll 4
  for (int k = 0; k < Hn; k += 4) {
    float4 av[4], wv[4];
#pragma unroll
    for (int i = 0; i < 4; ++i) { int r = tt * 4 + i; av[i] = *(const float4*)&As[r][SWZ(r, k)]; }
#pragma unroll
    for (int j = 0; j < 4; ++j) { int r = tg * 4 + j; wv[j] = *(const float4*)&Bs[r][SWZ(r, k)]; }
#pragma unroll
    for (int i = 0; i < 4; ++i)
#pragma unroll
      for (int j = 0; j < 4; ++j) {
        acc[i][j] = fmaf(av[i].x, wv[j].x, acc[i][j]);
        acc[i][j] = fmaf(av[i].y, wv[j].y, acc[i][j]);
        acc[i][j] = fmaf(av[i].z, wv[j].z, acc[i][j]);
        acc[i][j] = fmaf(av[i].w, wv[j].w, acc[i][j]);
      }
  }

#pragma unroll
  for (int j = 0; j < 4; ++j) {
    int g = g0 + tg * 4 + j;
    float bias = b1[g] + b2[g];
#pragma unroll
    for (int i = 0; i < 4; ++i) {
      int tc = t0 + tt * 4 + i;
      xg[((size_t)b * CHUNK + tc) * Gn + g] = __float2half(acc[i][j] + bias);
    }
  }
}

// ---------------- recurrence: one workgroup per batch element --------------
// Thread pair (2g,2g+1) owns gate row g: 64 Whh weights each in VGPRs.
// h broadcast from LDS; pair-combine via shfl_xor; elementwise on tids 0..127.
__global__ __launch_bounds__(1024) void k_rec(
    const float* __restrict__ Whh, const __half* __restrict__ xg,
    __half* __restrict__ hseq, float* __restrict__ state, int chunk)
{
  __shared__ float h_sh[Hn];
  __shared__ float gate_sh[Gn];
  const int b = blockIdx.x;
  const int tid = threadIdx.x;
  const int g = tid >> 1, half = tid & 1;

  float w[64];
  {
    const float4* wp = (const float4*)(Whh + (size_t)g * Hn + half * 64);
#pragma unroll
    for (int i = 0; i < 16; ++i) {
      float4 v = wp[i];
      w[4 * i + 0] = v.x; w[4 * i + 1] = v.y; w[4 * i + 2] = v.z; w[4 * i + 3] = v.w;
    }
  }

  float c_st = 0.f;
  if (tid < Hn) {
    float hv = 0.f;
    if (chunk != 0) { hv = state[b * 2 * Hn + tid]; c_st = state[b * 2 * Hn + Hn + tid]; }
    h_sh[tid] = hv;
  }
  __syncthreads();

  const __half* xp = xg + (size_t)b * CHUNK * Gn;
  __half* hp = hseq + ((size_t)b * Tn + chunk * CHUNK) * Hn;

  for (int t = 0; t < CHUNK; ++t) {
    float acc = 0.f;
    const float4* h4 = (const float4*)h_sh + half * 16;
#pragma unroll
    for (int i = 0; i < 16; ++i) {
      float4 hv = h4[i];
      acc = fmaf(w[4 * i + 0], hv.x, acc);
      acc = fmaf(w[4 * i + 1], hv.y, acc);
      acc = fmaf(w[4 * i + 2], hv.z, acc);
      acc = fmaf(w[4 * i + 3], hv.w, acc);
    }
    acc += __shfl_xor(acc, 1);
    if (half == 0) gate_sh[g] = acc + __half2float(xp[t * Gn + g]);
    __syncthreads();
    if (tid < Hn) {
      float ig = sigmoid_f(gate_sh[tid]);
      float fg = sigmoid_f(gate_sh[Hn + tid]);
      float gg = tanh_f(gate_sh[2 * Hn + tid]);
      float og = sigmoid_f(gate_sh[3 * Hn + tid]);
      c_st = fg * c_st + ig * gg;
      float hn = og * tanh_f(c_st);
      h_sh[tid] = hn;
      hp[t * Hn + tid] = __float2half(hn);
    }
    __syncthreads();
  }

  if (tid < Hn) {
    state[b * 2 * Hn + tid]      = h_sh[tid];
    state[b * 2 * Hn + Hn + tid] = c_st;
  }
}

// ---------------- final projection: logits = h_last @ Wc^T + bc ------------
__global__ __launch_bounds__(64) void k_final(
    const float* __restrict__ state, const float* __restrict__ Wc,
    const float* __restrict__ bc, float* __restrict__ out)
{
  int b = blockIdx.x, lane = threadIdx.x;
  const float* h = state + b * 2 * Hn;     // h half of state
  float s = h[lane] * Wc[lane] + h[lane + 64] * Wc[lane + 64];
#pragma unroll
  for (int o = 32; o; o >>= 1) s += __shfl_down(s, o);
  if (lane == 0) out[b] = s + bc[0];
}

extern "C" void kernel_launch(void* const* d_in, const int* in_sizes, int n_in,
                              void* d_out, int out_size, void* d_ws, size_t ws_size,
                              hipStream_t stream) {
  const float* x = (const float*)d_in[0];
  const float* Wih[3] = {(const float*)d_in[1], (const float*)d_in[5], (const float*)d_in[9]};
  const float* Whh[3] = {(const float*)d_in[2], (const float*)d_in[6], (const float*)d_in[10]};
  const float* bih[3] = {(const float*)d_in[3], (const float*)d_in[7], (const float*)d_in[11]};
  const float* bhh[3] = {(const float*)d_in[4], (const float*)d_in[8], (const float*)d_in[12]};
  const float* Wc = (const float*)d_in[13];
  const float* bc = (const float*)d_in[14];

  const size_t xg_bytes   = (size_t)Bn * CHUNK * Gn * sizeof(__half);  // 64 MB
  const size_t hseq_bytes = (size_t)Bn * Tn * Hn * sizeof(__half);     // 64 MB
  const size_t need = xg_bytes + hseq_bytes + (size_t)Bn * 2 * Hn * sizeof(float);
  if (ws_size < need) return;  // fail loudly (validation will catch) rather than corrupt

  char* ws = (char*)d_ws;
  __half* xg    = (__half*)ws;
  __half* hseq  = (__half*)(ws + xg_bytes);
  float*  state = (float*)(ws + xg_bytes + hseq_bytes);
  float*  out   = (float*)d_out;

  for (int l = 0; l < 3; ++l) {
    for (int c = 0; c < NCHUNK; ++c) {
      if (l == 0) {
        k_xg0<<<Bn * CHUNK * Gn / 256, 256, 0, stream>>>(x, Wih[0], bih[0], bhh[0], xg, c);
      } else {
        k_xgh<<<dim3(Gn / 64, CHUNK / 64, Bn), 256, 0, stream>>>(hseq, Wih[l], bih[l], bhh[l], xg, c);
      }
      k_rec<<<Bn, 1024, 0, stream>>>(Whh[l], xg, hseq, state, c);
    }
  }
  k_final<<<Bn, 64, 0, stream>>>(state, Wc, bc, out);
}

// Round 29
// 6162.389 us; speedup vs baseline: 1.6791x; 1.6791x over previous
//
#include <hip/hip_runtime.h>
#include <hip/hip_fp16.h>

#define Bn 128
#define Tn 2048
#define Hn 128
#define Gn 512            // 4*H gate rows
#define CHUNK 512
#define NCHUNK (Tn / CHUNK)

static_assert(CHUNK == 512 && Gn == 512, "index shifts assume 512");

typedef _Float16 half8 __attribute__((ext_vector_type(8)));
typedef float f32x4 __attribute__((ext_vector_type(4)));

__device__ __forceinline__ float sigmoid_f(float x) { return 1.f / (1.f + __expf(-x)); }
__device__ __forceinline__ float tanh_f(float x) {
  float e = __expf(-2.f * fabsf(x));
  float r = (1.f - e) / (1.f + e);
  return copysignf(r, x);
}

// ---------------- layer-0 input gates: xg = x @ Wih0^T + bih + bhh (K=4) ---
__global__ __launch_bounds__(256) void k_xg0(
    const float* __restrict__ x, const float* __restrict__ W,
    const float* __restrict__ b1, const float* __restrict__ b2,
    __half* __restrict__ xg, int chunk)
{
  int flat = blockIdx.x * 256 + threadIdx.x;       // (b*CHUNK + tc)*Gn + g
  int g  = flat & (Gn - 1);
  int tc = (flat >> 9) & (CHUNK - 1);
  int b  = flat >> 18;
  int t  = chunk * CHUNK + tc;
  float4 xv = *(const float4*)(x + ((size_t)b * Tn + t) * 4);
  float4 wv = *(const float4*)(W + g * 4);
  float s = b1[g] + b2[g] + xv.x * wv.x + xv.y * wv.y + xv.z * wv.z + xv.w * wv.w;
  xg[flat] = __float2half(s);
}

// ---------------- layers 1,2 input gates: xg = h_prev @ Wih^T + biases -----
// 64(t) x 64(g) tile, K=128 in one LDS pass. Rotation swizzle keeps float4
// LDS reads 16B-aligned and <=2-way bank conflicted.
#define SWZ(r, k) (((k) + ((((r) >> 2) << 2))) & (Hn - 1))

__global__ __launch_bounds__(256) void k_xgh(
    const __half* __restrict__ hseq, const float* __restrict__ W,
    const float* __restrict__ b1, const float* __restrict__ b2,
    __half* __restrict__ xg, int chunk)
{
  __shared__ float As[64][Hn];   // h tile   [t][k] (swizzled)
  __shared__ float Bs[64][Hn];   // Wih tile [g][k] (swizzled)
  const int tid = threadIdx.x;
  const int g0 = blockIdx.x * 64;
  const int t0 = blockIdx.y * 64;          // offset within chunk
  const int b  = blockIdx.z;

  const __half* Ab = hseq + ((size_t)b * Tn + chunk * CHUNK + t0) * Hn;
  const float*  Bb = W + (size_t)g0 * Hn;

#pragma unroll
  for (int p = 0; p < 8; ++p) {            // stage A: 64x128 halves -> fp32
    int f = p * 1024 + tid * 4;
    ushort4 v = ((const ushort4*)Ab)[f >> 2];
    int r = f >> 7, k = f & (Hn - 1);
    float* dst = &As[r][SWZ(r, k)];
    dst[0] = __half2float(*(const __half*)&v.x);
    dst[1] = __half2float(*(const __half*)&v.y);
    dst[2] = __half2float(*(const __half*)&v.z);
    dst[3] = __half2float(*(const __half*)&v.w);
  }
#pragma unroll
  for (int p = 0; p < 8; ++p) {            // stage B: 64x128 floats
    int f = p * 1024 + tid * 4;
    float4 v = ((const float4*)Bb)[f >> 2];
    int r = f >> 7, k = f & (Hn - 1);
    *(float4*)&Bs[r][SWZ(r, k)] = v;
  }
  __syncthreads();

  const int tg = tid & 15, tt = tid >> 4;
  float acc[4][4] = {};
#pragma unroll 4
  for (int k = 0; k < Hn; k += 4) {
    float4 av[4], wv[4];
#pragma unroll
    for (int i = 0; i < 4; ++i) { int r = tt * 4 + i; av[i] = *(const float4*)&As[r][SWZ(r, k)]; }
#pragma unroll
    for (int j = 0; j < 4; ++j) { int r = tg * 4 + j; wv[j] = *(const float4*)&Bs[r][SWZ(r, k)]; }
#pragma unroll
    for (int i = 0; i < 4; ++i)
#pragma unroll
      for (int j = 0; j < 4; ++j) {
        acc[i][j] = fmaf(av[i].x, wv[j].x, acc[i][j]);
        acc[i][j] = fmaf(av[i].y, wv[j].y, acc[i][j]);
        acc[i][j] = fmaf(av[i].z, wv[j].z, acc[i][j]);
        acc[i][j] = fmaf(av[i].w, wv[j].w, acc[i][j]);
      }
  }

#pragma unroll
  for (int j = 0; j < 4; ++j) {
    int g = g0 + tg * 4 + j;
    float bias = b1[g] + b2[g];
#pragma unroll
    for (int i = 0; i < 4; ++i) {
      int tc = t0 + tt * 4 + i;
      xg[((size_t)b * CHUNK + tc) * Gn + g] = __float2half(acc[i][j] + bias);
    }
  }
}

// ---------------- recurrence: one WG / batch element, MFMA matvec ----------
// 8 waves x 64 gate rows. Whh stays in A-fragments (VGPRs) for the whole
// dispatch. h is replicated across all 16 MFMA N-columns (B[k][n]=h[k]), so
// every output column equals the gate vector; per-step LDS traffic is just
// 4 ds_read_b128 per wave. D layout: col=lane&15, row=(lane>>4)*4+reg.
__global__ __launch_bounds__(512) void k_rec(
    const float* __restrict__ Whh, const __half* __restrict__ xg,
    __half* __restrict__ hseq, float* __restrict__ state, int chunk,
    int write_h)
{
  __shared__ float gate_sh[Gn];
  __shared__ _Float16 h_sh[Hn];
  const int b = blockIdx.x;
  const int tid = threadIdx.x;
  const int w = tid >> 6;          // wave 0..7 -> gate rows [64w, 64w+64)
  const int lane = tid & 63;
  const int m_in = lane & 15;      // row within 16x16 tile (A) / col (D)
  const int kq = lane >> 4;        // k-slice quadrant 0..3

  // A-fragments: lane holds row (64w + mt*16 + m_in), k = kt*32 + kq*8 .. +7
  half8 af[4][4];
#pragma unroll
  for (int mt = 0; mt < 4; ++mt)
#pragma unroll
    for (int kt = 0; kt < 4; ++kt) {
      const float* src = Whh + (size_t)(64 * w + mt * 16 + m_in) * Hn + kt * 32 + kq * 8;
      float4 a = *(const float4*)src;
      float4 c = *(const float4*)(src + 4);
      half8 v;
      v[0] = (_Float16)a.x; v[1] = (_Float16)a.y; v[2] = (_Float16)a.z; v[3] = (_Float16)a.w;
      v[4] = (_Float16)c.x; v[5] = (_Float16)c.y; v[6] = (_Float16)c.z; v[7] = (_Float16)c.w;
      af[mt][kt] = v;
    }

  float c_st = 0.f, h_cur = 0.f;
  if (tid < Hn) {
    if (chunk != 0) { h_cur = state[b * 2 * Hn + tid]; c_st = state[b * 2 * Hn + Hn + tid]; }
    h_sh[tid] = (_Float16)h_cur;
  }
  __syncthreads();

  const __half* xp = xg + (size_t)b * CHUNK * Gn;
  __half* hp = hseq + ((size_t)b * Tn + chunk * CHUNK) * Hn;

#pragma unroll 1   // keep code size bounded; body already has 16-MFMA ILP
  for (int t = 0; t < CHUNK; ++t) {
    // prefetch this step's xg (independent of h; latency hides under MFMA)
    float xgi, xgf, xgg, xgo;
    if (tid < Hn) {
      const __half* xrow = xp + (size_t)t * Gn;
      xgi = __half2float(xrow[tid]);
      xgf = __half2float(xrow[tid + 128]);
      xgg = __half2float(xrow[tid + 256]);
      xgo = __half2float(xrow[tid + 384]);
    }

    // B-fragments: k = kt*32 + kq*8 .. +7, replicated over all N columns
    half8 bf[4];
#pragma unroll
    for (int kt = 0; kt < 4; ++kt)
      bf[kt] = *(const half8*)&h_sh[kt * 32 + kq * 8];

#pragma unroll
    for (int mt = 0; mt < 4; ++mt) {
      f32x4 acc = {0.f, 0.f, 0.f, 0.f};
#pragma unroll
      for (int kt = 0; kt < 4; ++kt)
        acc = __builtin_amdgcn_mfma_f32_16x16x32_f16(af[mt][kt], bf[kt], acc, 0, 0, 0);
      if (m_in == 0)   // col-0 lanes hold rows kq*4+reg of this tile
        *(f32x4*)&gate_sh[64 * w + mt * 16 + kq * 4] = acc;
    }
    __syncthreads();

    if (tid < Hn) {
      float ig = sigmoid_f(gate_sh[tid] + xgi);
      float fg = sigmoid_f(gate_sh[Hn + tid] + xgf);
      float gg = tanh_f(gate_sh[2 * Hn + tid] + xgg);
      float og = sigmoid_f(gate_sh[3 * Hn + tid] + xgo);
      c_st = fg * c_st + ig * gg;
      float hn = og * tanh_f(c_st);
      h_cur = hn;
      h_sh[tid] = (_Float16)hn;
      if (write_h) hp[(size_t)t * Hn + tid] = __float2half(hn);
    }
    __syncthreads();
  }

  if (tid < Hn) {
    state[b * 2 * Hn + tid]      = h_cur;
    state[b * 2 * Hn + Hn + tid] = c_st;
  }
}

// ---------------- final projection: logits = h_last @ Wc^T + bc ------------
__global__ __launch_bounds__(64) void k_final(
    const float* __restrict__ state, const float* __restrict__ Wc,
    const float* __restrict__ bc, float* __restrict__ out)
{
  int b = blockIdx.x, lane = threadIdx.x;
  const float* h = state + b * 2 * Hn;     // h half of state
  float s = h[lane] * Wc[lane] + h[lane + 64] * Wc[lane + 64];
#pragma unroll
  for (int o = 32; o; o >>= 1) s += __shfl_down(s, o);
  if (lane == 0) out[b] = s + bc[0];
}

extern "C" void kernel_launch(void* const* d_in, const int* in_sizes, int n_in,
                              void* d_out, int out_size, void* d_ws, size_t ws_size,
                              hipStream_t stream) {
  const float* x = (const float*)d_in[0];
  const float* Wih[3] = {(const float*)d_in[1], (const float*)d_in[5], (const float*)d_in[9]};
  const float* Whh[3] = {(const float*)d_in[2], (const float*)d_in[6], (const float*)d_in[10]};
  const float* bih[3] = {(const float*)d_in[3], (const float*)d_in[7], (const float*)d_in[11]};
  const float* bhh[3] = {(const float*)d_in[4], (const float*)d_in[8], (const float*)d_in[12]};
  const float* Wc = (const float*)d_in[13];
  const float* bc = (const float*)d_in[14];

  const size_t xg_bytes   = (size_t)Bn * CHUNK * Gn * sizeof(__half);  // 64 MB
  const size_t hseq_bytes = (size_t)Bn * Tn * Hn * sizeof(__half);     // 64 MB
  const size_t need = xg_bytes + hseq_bytes + (size_t)Bn * 2 * Hn * sizeof(float);
  if (ws_size < need) return;  // fail loudly (validation will catch) rather than corrupt

  char* ws = (char*)d_ws;
  __half* xg    = (__half*)ws;
  __half* hseq  = (__half*)(ws + xg_bytes);
  float*  state = (float*)(ws + xg_bytes + hseq_bytes);
  float*  out   = (float*)d_out;

  for (int l = 0; l < 3; ++l) {
    for (int c = 0; c < NCHUNK; ++c) {
      if (l == 0) {
        k_xg0<<<Bn * CHUNK * Gn / 256, 256, 0, stream>>>(x, Wih[0], bih[0], bhh[0], xg, c);
      } else {
        k_xgh<<<dim3(Gn / 64, CHUNK / 64, Bn), 256, 0, stream>>>(hseq, Wih[l], bih[l], bhh[l], xg, c);
      }
      k_rec<<<Bn, 512, 0, stream>>>(Whh[l], xg, hseq, state, c, l != 2);
    }
  }
  k_final<<<Bn, 64, 0, stream>>>(state, Wc, bc, out);
}

// Round 39
// 5522.491 us; speedup vs baseline: 1.8737x; 1.1159x over previous
//
#include <hip/hip_runtime.h>
#include <hip/hip_fp16.h>

#define Bn 128
#define Tn 2048
#define Hn 128
#define Gn 512            // 4*H gate rows
#define CHUNK 512
#define NCHUNK (Tn / CHUNK)

static_assert(CHUNK == 512 && Gn == 512, "index shifts assume 512");

typedef _Float16 half8 __attribute__((ext_vector_type(8)));
typedef float f32x4 __attribute__((ext_vector_type(4)));

__device__ __forceinline__ float sigmoid_f(float x) { return 1.f / (1.f + __expf(-x)); }
__device__ __forceinline__ float tanh_f(float x) {
  float e = __expf(-2.f * fabsf(x));
  float r = (1.f - e) / (1.f + e);
  return copysignf(r, x);
}

// ---------------- layer-0 input gates: xg = x @ Wih0^T + bih + bhh (K=4) ---
__global__ __launch_bounds__(256) void k_xg0(
    const float* __restrict__ x, const float* __restrict__ W,
    const float* __restrict__ b1, const float* __restrict__ b2,
    __half* __restrict__ xg, int chunk)
{
  int flat = blockIdx.x * 256 + threadIdx.x;       // (b*CHUNK + tc)*Gn + g
  int g  = flat & (Gn - 1);
  int tc = (flat >> 9) & (CHUNK - 1);
  int b  = flat >> 18;
  int t  = chunk * CHUNK + tc;
  float4 xv = *(const float4*)(x + ((size_t)b * Tn + t) * 4);
  float4 wv = *(const float4*)(W + g * 4);
  float s = b1[g] + b2[g] + xv.x * wv.x + xv.y * wv.y + xv.z * wv.z + xv.w * wv.w;
  xg[flat] = __float2half(s);
}

// ---------------- layers 1,2 input gates: xg = h_prev @ Wih^T + biases -----
// 64(t) x 64(g) tile, K=128 in one LDS pass. Rotation swizzle keeps float4
// LDS reads 16B-aligned and <=2-way bank conflicted.
#define SWZ(r, k) (((k) + ((((r) >> 2) << 2))) & (Hn - 1))

__global__ __launch_bounds__(256) void k_xgh(
    const __half* __restrict__ hseq, const float* __restrict__ W,
    const float* __restrict__ b1, const float* __restrict__ b2,
    __half* __restrict__ xg, int chunk)
{
  __shared__ float As[64][Hn];   // h tile   [t][k] (swizzled)
  __shared__ float Bs[64][Hn];   // Wih tile [g][k] (swizzled)
  const int tid = threadIdx.x;
  const int g0 = blockIdx.x * 64;
  const int t0 = blockIdx.y * 64;          // offset within chunk
  const int b  = blockIdx.z;

  const __half* Ab = hseq + ((size_t)b * Tn + chunk * CHUNK + t0) * Hn;
  const float*  Bb = W + (size_t)g0 * Hn;

#pragma unroll
  for (int p = 0; p < 8; ++p) {            // stage A: 64x128 halves -> fp32
    int f = p * 1024 + tid * 4;
    ushort4 v = ((const ushort4*)Ab)[f >> 2];
    int r = f >> 7, k = f & (Hn - 1);
    float* dst = &As[r][SWZ(r, k)];
    dst[0] = __half2float(*(const __half*)&v.x);
    dst[1] = __half2float(*(const __half*)&v.y);
    dst[2] = __half2float(*(const __half*)&v.z);
    dst[3] = __half2float(*(const __half*)&v.w);
  }
#pragma unroll
  for (int p = 0; p < 8; ++p) {            // stage B: 64x128 floats
    int f = p * 1024 + tid * 4;
    float4 v = ((const float4*)Bb)[f >> 2];
    int r = f >> 7, k = f & (Hn - 1);
    *(float4*)&Bs[r][SWZ(r, k)] = v;
  }
  __syncthreads();

  const int tg = tid & 15, tt = tid >> 4;
  float acc[4][4] = {};
#pragma unroll 4
  for (int k = 0; k < Hn; k += 4) {
    float4 av[4], wv[4];
#pragma unroll
    for (int i = 0; i < 4; ++i) { int r = tt * 4 + i; av[i] = *(const float4*)&As[r][SWZ(r, k)]; }
#pragma unroll
    for (int j = 0; j < 4; ++j) { int r = tg * 4 + j; wv[j] = *(const float4*)&Bs[r][SWZ(r, k)]; }
#pragma unroll
    for (int i = 0; i < 4; ++i)
#pragma unroll
      for (int j = 0; j < 4; ++j) {
        acc[i][j] = fmaf(av[i].x, wv[j].x, acc[i][j]);
        acc[i][j] = fmaf(av[i].y, wv[j].y, acc[i][j]);
        acc[i][j] = fmaf(av[i].z, wv[j].z, acc[i][j]);
        acc[i][j] = fmaf(av[i].w, wv[j].w, acc[i][j]);
      }
  }

#pragma unroll
  for (int j = 0; j < 4; ++j) {
    int g = g0 + tg * 4 + j;
    float bias = b1[g] + b2[g];
#pragma unroll
    for (int i = 0; i < 4; ++i) {
      int tc = t0 + tt * 4 + i;
      xg[((size_t)b * CHUNK + tc) * Gn + g] = __float2half(acc[i][j] + bias);
    }
  }
}

// ---------------- recurrence: one WG / batch element, MFMA matvec ----------
// 8 waves x 64 gate rows; Whh resident in A-fragment VGPRs; h replicated
// across all 16 MFMA N-columns. xg loads are software-pipelined one step
// ahead so HBM latency (~900cy, xg is 2x L2) hides under a full step.
__global__ __launch_bounds__(512) void k_rec(
    const float* __restrict__ Whh, const __half* __restrict__ xg,
    __half* __restrict__ hseq, float* __restrict__ state, int chunk,
    int write_h)
{
  __shared__ float gate_sh[Gn];
  __shared__ _Float16 h_sh[Hn];
  const int b = blockIdx.x;
  const int tid = threadIdx.x;
  const int w = tid >> 6;          // wave 0..7 -> gate rows [64w, 64w+64)
  const int lane = tid & 63;
  const int m_in = lane & 15;      // row within 16x16 tile (A) / col (D)
  const int kq = lane >> 4;        // k-slice quadrant 0..3

  // A-fragments: lane holds row (64w + mt*16 + m_in), k = kt*32 + kq*8 .. +7
  half8 af[4][4];
#pragma unroll
  for (int mt = 0; mt < 4; ++mt)
#pragma unroll
    for (int kt = 0; kt < 4; ++kt) {
      const float* src = Whh + (size_t)(64 * w + mt * 16 + m_in) * Hn + kt * 32 + kq * 8;
      float4 a = *(const float4*)src;
      float4 c = *(const float4*)(src + 4);
      half8 v;
      v[0] = (_Float16)a.x; v[1] = (_Float16)a.y; v[2] = (_Float16)a.z; v[3] = (_Float16)a.w;
      v[4] = (_Float16)c.x; v[5] = (_Float16)c.y; v[6] = (_Float16)c.z; v[7] = (_Float16)c.w;
      af[mt][kt] = v;
    }

  float c_st = 0.f, h_cur = 0.f;
  if (tid < Hn) {
    if (chunk != 0) { h_cur = state[b * 2 * Hn + tid]; c_st = state[b * 2 * Hn + Hn + tid]; }
    h_sh[tid] = (_Float16)h_cur;
  }
  __syncthreads();

  const __half* xp = xg + (size_t)b * CHUNK * Gn;
  __half* hp = hseq + ((size_t)b * Tn + chunk * CHUNK) * Hn;

  // prologue: preload xg for t=0
  __half xi, xf, xgv, xo;
  if (tid < Hn) {
    xi  = xp[tid];
    xf  = xp[tid + 128];
    xgv = xp[tid + 256];
    xo  = xp[tid + 384];
  }

#pragma unroll 1   // keep code size bounded; body already has 16-MFMA ILP
  for (int t = 0; t < CHUNK; ++t) {
    // issue NEXT step's xg loads now; consumed in phase B of t+1 (~full
    // step of latency cover, > HBM ~900cy)
    __half ni, nf, ng, no;
    if (tid < Hn && t + 1 < CHUNK) {
      const __half* xrow = xp + (size_t)(t + 1) * Gn;
      ni = xrow[tid];
      nf = xrow[tid + 128];
      ng = xrow[tid + 256];
      no = xrow[tid + 384];
    }

    // B-fragments: k = kt*32 + kq*8 .. +7, replicated over all N columns
    half8 bf[4];
#pragma unroll
    for (int kt = 0; kt < 4; ++kt)
      bf[kt] = *(const half8*)&h_sh[kt * 32 + kq * 8];

#pragma unroll
    for (int mt = 0; mt < 4; ++mt) {
      f32x4 acc = {0.f, 0.f, 0.f, 0.f};
#pragma unroll
      for (int kt = 0; kt < 4; ++kt)
        acc = __builtin_amdgcn_mfma_f32_16x16x32_f16(af[mt][kt], bf[kt], acc, 0, 0, 0);
      if (m_in == 0)   // col-0 lanes hold rows kq*4+reg of this tile
        *(f32x4*)&gate_sh[64 * w + mt * 16 + kq * 4] = acc;
    }
    __syncthreads();

    if (tid < Hn) {
      float ig = sigmoid_f(gate_sh[tid] + __half2float(xi));
      float fg = sigmoid_f(gate_sh[Hn + tid] + __half2float(xf));
      float gg = tanh_f(gate_sh[2 * Hn + tid] + __half2float(xgv));
      float og = sigmoid_f(gate_sh[3 * Hn + tid] + __half2float(xo));
      c_st = fg * c_st + ig * gg;
      float hn = og * tanh_f(c_st);
      h_cur = hn;
      h_sh[tid] = (_Float16)hn;
      if (write_h) hp[(size_t)t * Hn + tid] = __float2half(hn);
    }
    __syncthreads();

    xi = ni; xf = nf; xgv = ng; xo = no;   // rotate pipeline registers
  }

  if (tid < Hn) {
    state[b * 2 * Hn + tid]      = h_cur;
    state[b * 2 * Hn + Hn + tid] = c_st;
  }
}

// ---------------- final projection: logits = h_last @ Wc^T + bc ------------
__global__ __launch_bounds__(64) void k_final(
    const float* __restrict__ state, const float* __restrict__ Wc,
    const float* __restrict__ bc, float* __restrict__ out)
{
  int b = blockIdx.x, lane = threadIdx.x;
  const float* h = state + b * 2 * Hn;     // h half of state
  float s = h[lane] * Wc[lane] + h[lane + 64] * Wc[lane + 64];
#pragma unroll
  for (int o = 32; o; o >>= 1) s += __shfl_down(s, o);
  if (lane == 0) out[b] = s + bc[0];
}

extern "C" void kernel_launch(void* const* d_in, const int* in_sizes, int n_in,
                              void* d_out, int out_size, void* d_ws, size_t ws_size,
                              hipStream_t stream) {
  const float* x = (const float*)d_in[0];
  const float* Wih[3] = {(const float*)d_in[1], (const float*)d_in[5], (const float*)d_in[9]};
  const float* Whh[3] = {(const float*)d_in[2], (const float*)d_in[6], (const float*)d_in[10]};
  const float* bih[3] = {(const float*)d_in[3], (const float*)d_in[7], (const float*)d_in[11]};
  const float* bhh[3] = {(const float*)d_in[4], (const float*)d_in[8], (const float*)d_in[12]};
  const float* Wc = (const float*)d_in[13];
  const float* bc = (const float*)d_in[14];

  const size_t xg_bytes   = (size_t)Bn * CHUNK * Gn * sizeof(__half);  // 64 MB
  const size_t hseq_bytes = (size_t)Bn * Tn * Hn * sizeof(__half);     // 64 MB
  const size_t need = xg_bytes + hseq_bytes + (size_t)Bn * 2 * Hn * sizeof(float);
  if (ws_size < need) return;  // fail loudly (validation will catch) rather than corrupt

  char* ws = (char*)d_ws;
  __half* xg    = (__half*)ws;
  __half* hseq  = (__half*)(ws + xg_bytes);
  float*  state = (float*)(ws + xg_bytes + hseq_bytes);
  float*  out   = (float*)d_out;

  for (int l = 0; l < 3; ++l) {
    for (int c = 0; c < NCHUNK; ++c) {
      if (l == 0) {
        k_xg0<<<Bn * CHUNK * Gn / 256, 256, 0, stream>>>(x, Wih[0], bih[0], bhh[0], xg, c);
      } else {
        k_xgh<<<dim3(Gn / 64, CHUNK / 64, Bn), 256, 0, stream>>>(hseq, Wih[l], bih[l], bhh[l], xg, c);
      }
      k_rec<<<Bn, 512, 0, stream>>>(Whh[l], xg, hseq, state, c, l != 2);
    }
  }
  k_final<<<Bn, 64, 0, stream>>>(state, Wc, bc, out);
}